// Round 4
// baseline (282.804 us; speedup 1.0000x reference)
//
#include <hip/hip_runtime.h>
#include <hip/hip_bf16.h>
#include <math.h>

// Problem constants
#define BATCH 8192
#define NB 9
#define NN 256
#define PMAX 8
#define HID 32
#define ZDIM 2304   // NB*NN

typedef short bf16x8 __attribute__((ext_vector_type(8)));   // 8 bf16 in 4 VGPRs
typedef float f32x4 __attribute__((ext_vector_type(4)));    // MFMA accumulator

static __device__ inline unsigned short f2bf(float f) {
    __hip_bfloat16 h = __float2bfloat16(f);
    return *reinterpret_cast<unsigned short*>(&h);
}

static __device__ inline uint4 pack8(float4 a, float4 b) {
    uint4 u;
    u.x = (unsigned)f2bf(a.x) | ((unsigned)f2bf(a.y) << 16);
    u.y = (unsigned)f2bf(a.z) | ((unsigned)f2bf(a.w) << 16);
    u.z = (unsigned)f2bf(b.x) | ((unsigned)f2bf(b.y) << 16);
    u.w = (unsigned)f2bf(b.z) | ((unsigned)f2bf(b.w) << 16);
    return u;
}

// ---------------- K0: pack weights to bf16 ------------------------------------
__global__ __launch_bounds__(256) void k_pack(
    const float* __restrict__ W, const float* __restrict__ gW1,
    unsigned short* __restrict__ Wb, unsigned short* __restrict__ WTb,
    unsigned short* __restrict__ gW1b, unsigned short* __restrict__ g1Tb) {
    int r = blockIdx.z;
    int t = threadIdx.x;
    if (r < 8) {
        __shared__ float tt[32][33];
        int i0 = blockIdx.y * 32;
        int j0 = blockIdx.x * 32;
        int tx = t & 31;
        int ty = t >> 5;
        const float* src = W + (size_t)r * 65536;
        #pragma unroll
        for (int s = 0; s < 32; s += 8) {
            float v = src[(size_t)(i0 + ty + s) * 256 + (j0 + tx)];
            tt[ty + s][tx] = v;
            Wb[(size_t)r * 65536 + (size_t)(i0 + ty + s) * 256 + (j0 + tx)] = f2bf(v);
        }
        __syncthreads();
        #pragma unroll
        for (int s = 0; s < 32; s += 8)
            WTb[(size_t)r * 65536 + (size_t)(j0 + ty + s) * 256 + (i0 + tx)] = f2bf(tt[tx][ty + s]);
    } else {
        int tg = (blockIdx.y * 8 + blockIdx.x) * 256 + t;       // 0..16383
        for (int e = tg; e < 73728; e += 16384) {
            float v = gW1[e];
            unsigned short b = f2bf(v);
            gW1b[e] = b;
            int k = e >> 13, n = (e >> 5) & 255, h = e & 31;
            g1Tb[(size_t)(k * 32 + h) * 256 + n] = b;
        }
    }
}

// -------------------- K1 (MFMA): d1 -> bf16 chunk-swizzled layout --------------
// One WG = 128 batch rows of one block k. d1b[k][rg][ci] chunk ci holds rows
// m=(ci&15)+16*(ci>>6), k-offset q=(ci>>4)&3 (same layout as cross K-tail LDS).
__global__ __launch_bounds__(256) void k_mlp(
    const float* __restrict__ z, const unsigned short* __restrict__ g1Tb,
    const float* __restrict__ gb1, const float* __restrict__ gW2,
    const float* __restrict__ gb2, const float* __restrict__ gW3,
    uint4* __restrict__ d1b) {
    __shared__ uint4 As4[512];    // 128 rows x 32 k bf16 (reused for h1/da2/d1)
    __shared__ uint4 Bw[1024];    // gW1^T: 32 h x 256 n bf16, 8 chunk-regions
    __shared__ uint4 W2Ts4[128];  // W2^T fragment layout
    __shared__ uint4 W2Ns4[128];  // W2 natural fragment layout

    int t = threadIdx.x;
    int lane = t & 63;
    int w = t >> 6;
    int k = blockIdx.y;
    int bx = blockIdx.x;
    int b0 = bx * 128;

    // ---- stage Bw (linear chunk->thread: conflict-free writes) ----
    const unsigned short* bsrc = g1Tb + (size_t)k * 8192;
    for (int e = t; e < 1024; e += 256) {
        int c = e >> 7, rest = e & 127;
        int h = (rest & 15) + ((rest >> 6) << 4);
        int q2 = (rest >> 4) & 3;
        Bw[e] = *(const uint4*)(bsrc + (size_t)h * 256 + c * 32 + q2 * 8);
    }
    const float* gw2 = gW2 + (size_t)k * 1024;
    unsigned short* w2t = (unsigned short*)W2Ts4;
    unsigned short* w2n = (unsigned short*)W2Ns4;
    for (int e = t; e < 1024; e += 256) {
        int n = e >> 5, kk = e & 31;
        int q2 = kk >> 3, jj = kk & 7;
        int ci = (n & 15) + 16 * q2 + 64 * (n >> 4);
        w2t[ci * 8 + jj] = f2bf(gw2[kk * 32 + n]);   // W2T[g=n][h=kk]
        w2n[ci * 8 + jj] = f2bf(gw2[n * 32 + kk]);   // W2N[h=n][g=kk]
    }

    int m_lin = (t & 15) + ((t >> 6) << 4);
    int q = (t >> 4) & 3;
    const float* zbase = z + (size_t)b0 * ZDIM + k * 256 + q * 8;

    // ---- layer-1 GEMM with prefetch pipeline ----
    float4 fa[2][2];
    #pragma unroll
    for (int pp = 0; pp < 2; ++pp) {
        const float* p = zbase + (size_t)(m_lin + 64 * pp) * ZDIM;
        fa[pp][0] = ((const float4*)p)[0];
        fa[pp][1] = ((const float4*)p)[1];
    }
    f32x4 acc1[2][2];
    #pragma unroll
    for (int i = 0; i < 2; ++i)
        #pragma unroll
        for (int j = 0; j < 2; ++j) acc1[i][j] = (f32x4){0.f, 0.f, 0.f, 0.f};

    for (int c = 0; c < 8; ++c) {
        __syncthreads();
        #pragma unroll
        for (int pp = 0; pp < 2; ++pp)
            As4[256 * pp + t] = pack8(fa[pp][0], fa[pp][1]);
        __syncthreads();
        if (c < 7) {
            #pragma unroll
            for (int pp = 0; pp < 2; ++pp) {
                const float* p = zbase + (size_t)(m_lin + 64 * pp) * ZDIM + (c + 1) * 32;
                fa[pp][0] = ((const float4*)p)[0];
                fa[pp][1] = ((const float4*)p)[1];
            }
        }
        bf16x8 af[2], bfr[2];
        #pragma unroll
        for (int i = 0; i < 2; ++i) af[i] = __builtin_bit_cast(bf16x8, As4[lane + (w * 2 + i) * 64]);
        #pragma unroll
        for (int j = 0; j < 2; ++j) bfr[j] = __builtin_bit_cast(bf16x8, Bw[c * 128 + lane + j * 64]);
        #pragma unroll
        for (int i = 0; i < 2; ++i)
            #pragma unroll
            for (int j = 0; j < 2; ++j)
                acc1[i][j] = __builtin_amdgcn_mfma_f32_16x16x32_bf16(af[i], bfr[j], acc1[i][j], 0, 0, 0);
    }

    // ---- bias + silu; h1 -> LDS chunk layout ----
    int cq = lane >> 4;
    int ci16 = lane & 15;
    float b1v[2], b2v[2], g3v[2];
    #pragma unroll
    for (int j = 0; j < 2; ++j) {
        b1v[j] = gb1[k * 32 + j * 16 + ci16];
        b2v[j] = gb2[k * 32 + j * 16 + ci16];
        g3v[j] = gW3[k * 32 + j * 16 + ci16];
    }
    unsigned short* Hs = (unsigned short*)As4;
    float sp1[2][2][4];
    __syncthreads();
    #pragma unroll
    for (int i = 0; i < 2; ++i)
        #pragma unroll
        for (int j = 0; j < 2; ++j)
            #pragma unroll
            for (int r = 0; r < 4; ++r) {
                float a1 = acc1[i][j][r] + b1v[j];
                float s1 = 1.f / (1.f + __expf(-a1));
                sp1[i][j][r] = s1 * (1.f + a1 * (1.f - s1));
                int row = w * 32 + i * 16 + cq * 4 + r;
                int col = j * 16 + ci16;
                int chunk = (row & 15) + 16 * (col >> 3) + 64 * (row >> 4);
                Hs[chunk * 8 + (col & 7)] = f2bf(a1 * s1);
            }
    __syncthreads();

    // ---- layer-2 ----
    bf16x8 af2[2], wf[2];
    #pragma unroll
    for (int i = 0; i < 2; ++i) af2[i] = __builtin_bit_cast(bf16x8, As4[lane + (w * 2 + i) * 64]);
    #pragma unroll
    for (int j = 0; j < 2; ++j) wf[j] = __builtin_bit_cast(bf16x8, W2Ts4[lane + j * 64]);
    f32x4 acc2[2][2];
    #pragma unroll
    for (int i = 0; i < 2; ++i)
        #pragma unroll
        for (int j = 0; j < 2; ++j) {
            acc2[i][j] = (f32x4){0.f, 0.f, 0.f, 0.f};
            acc2[i][j] = __builtin_amdgcn_mfma_f32_16x16x32_bf16(af2[i], wf[j], acc2[i][j], 0, 0, 0);
        }

    // ---- da2 -> LDS ----
    __syncthreads();
    #pragma unroll
    for (int i = 0; i < 2; ++i)
        #pragma unroll
        for (int j = 0; j < 2; ++j)
            #pragma unroll
            for (int r = 0; r < 4; ++r) {
                float a2 = acc2[i][j][r] + b2v[j];
                float s2 = 1.f / (1.f + __expf(-a2));
                float da2 = g3v[j] * s2 * (1.f + a2 * (1.f - s2));
                int row = w * 32 + i * 16 + cq * 4 + r;
                int col = j * 16 + ci16;
                int chunk = (row & 15) + 16 * (col >> 3) + 64 * (row >> 4);
                Hs[chunk * 8 + (col & 7)] = f2bf(da2);
            }
    __syncthreads();

    // ---- layer-3: dh1 = da2 @ W2^T; d1 = dh1 * silu'(a1) ----
    bf16x8 af3[2], wg[2];
    #pragma unroll
    for (int i = 0; i < 2; ++i) af3[i] = __builtin_bit_cast(bf16x8, As4[lane + (w * 2 + i) * 64]);
    #pragma unroll
    for (int j = 0; j < 2; ++j) wg[j] = __builtin_bit_cast(bf16x8, W2Ns4[lane + j * 64]);
    float d1v[2][2][4];
    #pragma unroll
    for (int i = 0; i < 2; ++i)
        #pragma unroll
        for (int j = 0; j < 2; ++j) {
            f32x4 a3 = (f32x4){0.f, 0.f, 0.f, 0.f};
            a3 = __builtin_amdgcn_mfma_f32_16x16x32_bf16(af3[i], wg[j], a3, 0, 0, 0);
            #pragma unroll
            for (int r = 0; r < 4; ++r) d1v[i][j][r] = a3[r] * sp1[i][j][r];
        }
    __syncthreads();   // all af3 reads of As4 done
    #pragma unroll
    for (int i = 0; i < 2; ++i)
        #pragma unroll
        for (int j = 0; j < 2; ++j)
            #pragma unroll
            for (int r = 0; r < 4; ++r) {
                int row = w * 32 + i * 16 + cq * 4 + r;
                int col = j * 16 + ci16;
                int chunk = (row & 15) + 16 * (col >> 3) + 64 * (row >> 4);
                Hs[chunk * 8 + (col & 7)] = f2bf(d1v[i][j][r]);
            }
    __syncthreads();
    uint4* dst = d1b + ((size_t)k * 64 + bx) * 512;
    #pragma unroll
    for (int pp = 0; pp < 2; ++pp)
        dst[256 * pp + t] = As4[256 * pp + t];
}

// ---- K2 (MFMA, fused): bx<4 -> hi path (cols 2048+), bx>=4 -> lo path ---------
// hi: out[:,2048+i0 .. +64] = -(sum_m x_m @ W[7-m]^T + d1_8 @ gW1[8]^T), 65 iters
// lo: out[:,k*256+jb ..+128] = -(z8 @ W[7-k] + d1_k @ gW1[k]^T), 9 iters
// 5 WG/CU mix: short lo WGs fill latency stalls of long hi WGs.
__global__ __launch_bounds__(256) void k_cross(
    const float* __restrict__ z, const uint4* __restrict__ d1b,
    const unsigned short* __restrict__ Wb, const unsigned short* __restrict__ WTb,
    const unsigned short* __restrict__ gW1b, float* __restrict__ out) {
    __shared__ uint4 As4[512];   // 128 rows x 32 k bf16
    __shared__ uint4 Bs4[512];   // up to 128 cols x 32 k bf16

    int t = threadIdx.x;
    int lane = t & 63;
    int w = t >> 6;
    int by = blockIdx.y;
    int b0 = by * 128;
    int bx = blockIdx.x;
    int m_lin = (t & 15) + ((t >> 6) << 4);
    int q = (t >> 4) & 3;
    int rquad = lane >> 4;
    int cidx = lane & 15;

    if (bx >= 4) {
        // ================= lo path =================
        int kb_ = bx - 4;                 // 0..15
        int k = kb_ >> 1, jb = (kb_ & 1) * 128;
        const float* Az = z + (size_t)b0 * ZDIM + 2048 + q * 8;
        const uint4* Ad = d1b + ((size_t)k * 64 + by) * 512;
        const unsigned short* Bm = WTb + (size_t)(7 - k) * 65536 + (size_t)jb * 256 + q * 8;
        const unsigned short* Be = gW1b + ((size_t)k * 256 + jb) * 32 + q * 8;
        int wr = w >> 1, wc = w & 1;

        float4 fa[2][2];
        uint4 au[2], bu[2];
        #pragma unroll
        for (int pp = 0; pp < 2; ++pp) {
            const float* p = Az + (size_t)(m_lin + 64 * pp) * ZDIM;
            fa[pp][0] = ((const float4*)p)[0];
            fa[pp][1] = ((const float4*)p)[1];
            bu[pp] = *(const uint4*)(Bm + (size_t)(m_lin + 64 * pp) * 256);
        }
        f32x4 acc[4][4];
        #pragma unroll
        for (int i = 0; i < 4; ++i)
            #pragma unroll
            for (int j = 0; j < 4; ++j) acc[i][j] = (f32x4){0.f, 0.f, 0.f, 0.f};

        for (int c = 0; c < 9; ++c) {
            bool tail = (c == 8);
            __syncthreads();
            #pragma unroll
            for (int pp = 0; pp < 2; ++pp) {
                As4[256 * pp + t] = tail ? au[pp] : pack8(fa[pp][0], fa[pp][1]);
                Bs4[256 * pp + t] = bu[pp];
            }
            __syncthreads();
            if (c < 8) {
                int cn = c + 1;
                if (cn < 8) {
                    #pragma unroll
                    for (int pp = 0; pp < 2; ++pp) {
                        const float* p = Az + (size_t)(m_lin + 64 * pp) * ZDIM + cn * 32;
                        fa[pp][0] = ((const float4*)p)[0];
                        fa[pp][1] = ((const float4*)p)[1];
                        bu[pp] = *(const uint4*)(Bm + (size_t)(m_lin + 64 * pp) * 256 + cn * 32);
                    }
                } else {
                    #pragma unroll
                    for (int pp = 0; pp < 2; ++pp) {
                        au[pp] = Ad[256 * pp + t];
                        bu[pp] = *(const uint4*)(Be + (size_t)(m_lin + 64 * pp) * 32);
                    }
                }
            }
            bf16x8 af[4], bf[4];
            #pragma unroll
            for (int i = 0; i < 4; ++i) af[i] = __builtin_bit_cast(bf16x8, As4[lane + (wr * 4 + i) * 64]);
            #pragma unroll
            for (int j = 0; j < 4; ++j) bf[j] = __builtin_bit_cast(bf16x8, Bs4[lane + (wc * 4 + j) * 64]);
            #pragma unroll
            for (int i = 0; i < 4; ++i)
                #pragma unroll
                for (int j = 0; j < 4; ++j)
                    acc[i][j] = __builtin_amdgcn_mfma_f32_16x16x32_bf16(af[i], bf[j], acc[i][j], 0, 0, 0);
        }
        #pragma unroll
        for (int i = 0; i < 4; ++i)
            #pragma unroll
            for (int j = 0; j < 4; ++j) {
                float* o = out + (size_t)(b0 + wr * 64 + i * 16 + rquad * 4) * ZDIM
                         + (k * 256 + jb + wc * 64 + j * 16 + cidx);
                #pragma unroll
                for (int r = 0; r < 4; ++r)
                    o[(size_t)r * ZDIM] = -acc[i][j][r];
            }
    } else {
        // ================= hi path =================
        int i0 = bx * 64;
        const float* Az = z + (size_t)b0 * ZDIM + q * 8;
        const uint4* Ad = d1b + ((size_t)8 * 64 + by) * 512;
        const unsigned short* Be = gW1b + (size_t)(8 * 256 + i0) * 32 + q * 8;
        int bn = m_lin;                   // 0..63

        float4 fa[2][2];
        uint4 au[2], bu;
        #pragma unroll
        for (int pp = 0; pp < 2; ++pp) {
            const float* p = Az + (size_t)(m_lin + 64 * pp) * ZDIM;
            fa[pp][0] = ((const float4*)p)[0];
            fa[pp][1] = ((const float4*)p)[1];
        }
        bu = *(const uint4*)(Wb + (size_t)7 * 65536 + (size_t)(i0 + bn) * 256 + q * 8);

        f32x4 acc[2][4];
        #pragma unroll
        for (int i = 0; i < 2; ++i)
            #pragma unroll
            for (int j = 0; j < 4; ++j) acc[i][j] = (f32x4){0.f, 0.f, 0.f, 0.f};

        for (int c = 0; c < 65; ++c) {
            bool tail = (c == 64);
            __syncthreads();
            #pragma unroll
            for (int pp = 0; pp < 2; ++pp)
                As4[256 * pp + t] = tail ? au[pp] : pack8(fa[pp][0], fa[pp][1]);
            Bs4[t] = bu;
            __syncthreads();
            if (c < 64) {
                int cn = c + 1;
                if (cn < 64) {
                    int kb = cn * 32;
                    #pragma unroll
                    for (int pp = 0; pp < 2; ++pp) {
                        const float* p = Az + (size_t)(m_lin + 64 * pp) * ZDIM + kb;
                        fa[pp][0] = ((const float4*)p)[0];
                        fa[pp][1] = ((const float4*)p)[1];
                    }
                    int lag = cn >> 3;
                    int j0 = kb & 255;
                    bu = *(const uint4*)(Wb + (size_t)(7 - lag) * 65536
                                         + (size_t)(i0 + bn) * 256 + j0 + q * 8);
                } else {
                    #pragma unroll
                    for (int pp = 0; pp < 2; ++pp) au[pp] = Ad[256 * pp + t];
                    bu = *(const uint4*)(Be + (size_t)bn * 32);
                }
            }
            bf16x8 af[2], bf[4];
            #pragma unroll
            for (int i = 0; i < 2; ++i) af[i] = __builtin_bit_cast(bf16x8, As4[lane + (w * 2 + i) * 64]);
            #pragma unroll
            for (int j = 0; j < 4; ++j) bf[j] = __builtin_bit_cast(bf16x8, Bs4[lane + j * 64]);
            #pragma unroll
            for (int i = 0; i < 2; ++i)
                #pragma unroll
                for (int j = 0; j < 4; ++j)
                    acc[i][j] = __builtin_amdgcn_mfma_f32_16x16x32_bf16(af[i], bf[j], acc[i][j], 0, 0, 0);
        }
        #pragma unroll
        for (int i = 0; i < 2; ++i)
            #pragma unroll
            for (int j = 0; j < 4; ++j) {
                float* o = out + (size_t)(b0 + w * 32 + i * 16 + rquad * 4) * ZDIM
                         + (2048 + i0 + j * 16 + cidx);
                #pragma unroll
                for (int r = 0; r < 4; ++r)
                    o[(size_t)r * ZDIM] = -acc[i][j][r];
            }
    }
}

extern "C" void kernel_launch(void* const* d_in, const int* in_sizes, int n_in,
                              void* d_out, int out_size, void* d_ws, size_t ws_size,
                              hipStream_t stream) {
    const float* z   = (const float*)d_in[0];
    const float* gW1 = (const float*)d_in[1];
    const float* gb1 = (const float*)d_in[2];
    const float* gW2 = (const float*)d_in[3];
    const float* gb2 = (const float*)d_in[4];
    const float* gW3 = (const float*)d_in[5];
    // d_in[6] = gb3: constant, no grad
    const float* W   = (const float*)d_in[7];
    float* out = (float*)d_out;

    char* ws = (char*)d_ws;
    uint4*          d1b  = (uint4*)ws;                         // 9*64*512 uint4 = 4.7 MB
    unsigned short* Wb   = (unsigned short*)(ws + 4718592);    // 524288 bf16
    unsigned short* WTb  = Wb + 524288;                        // 524288 bf16
    unsigned short* gW1b = WTb + 524288;                       // 73728 bf16
    unsigned short* g1Tb = gW1b + 73728;                       // 73728 bf16 (~7 MB total)

    k_pack<<<dim3(8, 8, 9), 256, 0, stream>>>(W, gW1, Wb, WTb, gW1b, g1Tb);
    k_mlp<<<dim3(64, 9), 256, 0, stream>>>(z, g1Tb, gb1, gW2, gb2, gW3, d1b);
    k_cross<<<dim3(20, 64), 256, 0, stream>>>(z, d1b, Wb, WTb, gW1b, out);
}